// Round 3
// baseline (301.192 us; speedup 1.0000x reference)
//
#include <hip/hip_runtime.h>
#include <hip/hip_bf16.h>
#include <stdint.h>

// Problem constants: B=8, S=2048, D_IN=4096, D_OUT=4096
#define MROWS 16384   // B*S
#define DIN   4096
#define DOUT  4096
#define KEFF  1024    // DIN * 2/8 (mask keeps d%8 in {0,2})

typedef __attribute__((ext_vector_type(8))) __bf16 bf16x8;
typedef __attribute__((ext_vector_type(4))) float f32x4;

#define AS1 __attribute__((address_space(1)))
#define AS3 __attribute__((address_space(3)))

__device__ __forceinline__ uint32_t f2bf_rne(float f) {
  union { float f; uint32_t u; } v; v.f = f;
  uint32_t u = v.u;
  return (u + 0x7fffu + ((u >> 16) & 1u)) >> 16;
}

// Gather 2-of-8 (positions 0,2 of each group of 8), fp32 -> bf16, pack pairs.
__global__ void venom_gather(const float* __restrict__ src,
                             uint32_t* __restrict__ dst, int ngroups) {
  int stride = gridDim.x * blockDim.x;
  for (int i = blockIdx.x * blockDim.x + threadIdx.x; i < ngroups; i += stride) {
    const float4 v = *reinterpret_cast<const float4*>(src + (size_t)i * 8);
    dst[i] = f2bf_rne(v.x) | (f2bf_rne(v.z) << 16);
  }
}

// ------------- 256x256 bf16 GEMM, counted-vmcnt pipeline (T1..T5) -------------
// A = Xg [MROWS][KEFF] bf16 row-major, B = Wg [DOUT][KEFF] bf16 row-major (B^T).
// C[m][n] = sum_k A[m][k]*B[n][k] + bias[n], fp32 row-major.
#define BM 256
#define BN 256
#define BK 64
#define NT (KEFF / BK)   // 16

// LDS half-tile layout: [128 superrows][128B]; superrow sr holds rows 2sr,2sr+1
// (32 k-elems = 64B each), 8x16B slots XOR-swizzled by (sr&7).
__device__ __forceinline__ int swz_off(int R, int lg) {
  int sr = R >> 1;
  return sr * 128 + (((((R & 1) << 2) | lg) ^ (sr & 7)) << 4);
}

__global__ __launch_bounds__(512, 2) void venom_gemm(
    const __bf16* __restrict__ A, const __bf16* __restrict__ Bm,
    const float* __restrict__ bias, float* __restrict__ C) {
  // [dbuf][k-half][16KB half-tile] for A and B: 128 KiB total
  __shared__ __bf16 As[2][2][128 * 64];
  __shared__ __bf16 Bs[2][2][128 * 64];

  const int nblkN = DOUT / BN;  // 16
  // XCD-aware bijective swizzle (grid=1024, %8==0)
  int nwg = gridDim.x;
  int cpx = nwg >> 3;
  int bid = blockIdx.x;
  int swz = (bid & 7) * cpx + (bid >> 3);
  int mblk = swz / nblkN;
  int nblk = swz % nblkN;

  int t = threadIdx.x;
  int wid = t >> 6, l = t & 63;
  int wr = wid >> 2, wc = wid & 3;   // 2x4 wave grid; wave owns 128x64 of C
  int lr = l & 15, lg = l >> 4;

  const __bf16* Ag = A + (size_t)(mblk * BM) * KEFF;
  const __bf16* Bg = Bm + (size_t)(nblk * BN) * KEFF;

  f32x4 acc[8][4] = {};

  // Stage one k-half (A 16KB + B 16KB = 4 loads/thread). Linear LDS dest,
  // inverse-swizzled global source (rule #21).
  auto stage_half = [&](int buf, int kt, int kh) {
    const int k0 = kt * BK + kh * 32;
    #pragma unroll
    for (int i = 0; i < 2; ++i) {
      int e = i * 512 + t;           // 16B chunk 0..1023
      int sr = e >> 3;
      int s = (e & 7) ^ (sr & 7);    // unswizzled slot
      int row = sr * 2 + (s >> 2);
      int koff = (s & 3) * 8;
      __builtin_amdgcn_global_load_lds(
          (const AS1 uint32_t*)(Ag + (size_t)row * KEFF + k0 + koff),
          ((AS3 uint32_t*)&As[buf][kh][0]) + e * 4, 16, 0, 0);
      __builtin_amdgcn_global_load_lds(
          (const AS1 uint32_t*)(Bg + (size_t)row * KEFF + k0 + koff),
          ((AS3 uint32_t*)&Bs[buf][kh][0]) + e * 4, 16, 0, 0);
    }
  };

  // Prologue: both halves of tile 0; wait only for half 0 (vmcnt counts loads:
  // 8 outstanding, keep newest 4 in flight).
  stage_half(0, 0, 0);
  stage_half(0, 0, 1);
  asm volatile("s_waitcnt vmcnt(4)" ::: "memory");
  __builtin_amdgcn_s_barrier();

  bf16x8 bfrag[4];

  for (int kt = 0; kt < NT; ++kt) {
    const int cur = kt & 1, nxt = cur ^ 1, t1 = kt + 1;

    // Phases (mh,kh): (0,0),(1,0),(0,1),(1,1). Stage t+1's kh at phases 0,2.
    // Waits: end of ph1 gates kh1 reads (vmcnt 4: t+1-kh0 stays in flight);
    //        end of ph3 gates next tile's kh0 reads (vmcnt 4: t+1-kh1 in flight).
    #pragma unroll
    for (int ph = 0; ph < 4; ++ph) {
      const int mh = ph & 1, kh = ph >> 1;
      const char* aB = (const char*)&As[cur][kh][0];
      bf16x8 af[4];
      #pragma unroll
      for (int mi = 0; mi < 4; ++mi)
        af[mi] = *(const bf16x8*)(aB + swz_off(wr * 128 + mh * 64 + mi * 16 + lr, lg));
      if (mh == 0) {
        const char* bB = (const char*)&Bs[cur][kh][0];
        #pragma unroll
        for (int ni = 0; ni < 4; ++ni)
          bfrag[ni] = *(const bf16x8*)(bB + swz_off(wc * 64 + ni * 16 + lr, lg));
        if (t1 < NT) stage_half(nxt, t1, kh);
      }

      __builtin_amdgcn_s_barrier();
      __builtin_amdgcn_s_setprio(1);
      #pragma unroll
      for (int mi = 0; mi < 4; ++mi)
        #pragma unroll
        for (int ni = 0; ni < 4; ++ni)
          acc[mh * 4 + mi][ni] = __builtin_amdgcn_mfma_f32_16x16x32_bf16(
              af[mi], bfrag[ni], acc[mh * 4 + mi][ni], 0, 0, 0);
      __builtin_amdgcn_s_setprio(0);

      if (ph == 1) {
        if (t1 < NT) asm volatile("s_waitcnt vmcnt(4)" ::: "memory");
        else         asm volatile("s_waitcnt vmcnt(0)" ::: "memory");
        __builtin_amdgcn_s_barrier();
      } else if (ph == 3) {
        if (t1 < NT) {
          asm volatile("s_waitcnt vmcnt(4)" ::: "memory");
          __builtin_amdgcn_s_barrier();
        }
      } else {
        __builtin_amdgcn_s_barrier();
      }
    }
  }

  // Epilogue: C/D layout col=lane&15, row=(lane>>4)*4+j  [m89/m91]
  int colbase = nblk * BN + wc * 64;
  int rowbase = mblk * BM + wr * 128;
  #pragma unroll
  for (int mh = 0; mh < 2; ++mh)
    #pragma unroll
    for (int mi = 0; mi < 4; ++mi) {
      int row0 = rowbase + mh * 64 + mi * 16 + lg * 4;
      #pragma unroll
      for (int ni = 0; ni < 4; ++ni) {
        int col = colbase + ni * 16 + lr;
        float bv = bias[col];
        f32x4 cv = acc[mh * 4 + mi][ni];
        #pragma unroll
        for (int j = 0; j < 4; ++j)
          C[(size_t)(row0 + j) * DOUT + col] = cv[j] + bv;
      }
    }
}

// Correct-but-slow fallback if workspace is too small (should not trigger).
__global__ void venom_naive(const float* __restrict__ x, const float* __restrict__ w,
                            const float* __restrict__ bias, float* __restrict__ out) {
  size_t total = (size_t)MROWS * DOUT;
  size_t stride = (size_t)gridDim.x * blockDim.x;
  for (size_t idx = (size_t)blockIdx.x * blockDim.x + threadIdx.x; idx < total;
       idx += stride) {
    int m = (int)(idx / DOUT), n = (int)(idx % DOUT);
    const float* xr = x + (size_t)m * DIN;
    const float* wr = w + (size_t)n * DIN;
    float s = 0.f;
    for (int g = 0; g < DIN / 8; ++g)
      s += xr[g * 8] * wr[g * 8] + xr[g * 8 + 2] * wr[g * 8 + 2];
    out[idx] = s + bias[n];
  }
}

extern "C" void kernel_launch(void* const* d_in, const int* in_sizes, int n_in,
                              void* d_out, int out_size, void* d_ws, size_t ws_size,
                              hipStream_t stream) {
  const float* x    = (const float*)d_in[0];
  const float* wgt  = (const float*)d_in[1];
  const float* bias = (const float*)d_in[2];
  float* out = (float*)d_out;

  const size_t xg_bytes = (size_t)MROWS * KEFF * 2;  // 33.5 MB
  const size_t wg_bytes = (size_t)DOUT * KEFF * 2;   //  8.4 MB

  if (ws_size < xg_bytes + wg_bytes) {
    venom_naive<<<2048, 256, 0, stream>>>(x, wgt, bias, out);
    return;
  }

  uint32_t* xg = (uint32_t*)d_ws;
  uint32_t* wg = (uint32_t*)((char*)d_ws + xg_bytes);

  venom_gather<<<2048, 256, 0, stream>>>(x, xg, MROWS * (DIN / 8));
  venom_gather<<<512, 256, 0, stream>>>(wgt, wg, DOUT * (DIN / 8));

  venom_gemm<<<(MROWS / BM) * (DOUT / BN), 512, 0, stream>>>(
      (const __bf16*)xg, (const __bf16*)wg, bias, out);
}

// Round 4
// 281.806 us; speedup vs baseline: 1.0688x; 1.0688x over previous
//
#include <hip/hip_runtime.h>
#include <hip/hip_bf16.h>
#include <stdint.h>

// Problem constants: B=8, S=2048, D_IN=4096, D_OUT=4096
#define MROWS 16384   // B*S
#define DIN   4096
#define DOUT  4096
#define KEFF  1024    // DIN * 2/8 (mask keeps d%8 in {0,2})

typedef __attribute__((ext_vector_type(8))) __bf16 bf16x8;
typedef __attribute__((ext_vector_type(4))) float f32x4;

#define AS1 __attribute__((address_space(1)))
#define AS3 __attribute__((address_space(3)))

__device__ __forceinline__ uint32_t f2bf_rne(float f) {
  union { float f; uint32_t u; } v; v.f = f;
  uint32_t u = v.u;
  return (u + 0x7fffu + ((u >> 16) & 1u)) >> 16;
}

// Gather 2-of-8 (positions 0,2 of each group of 8), fp32 -> bf16.
// 2 groups per thread, uint2 store (8B contiguous per lane).
__global__ void venom_gather2(const float* __restrict__ src,
                              uint2* __restrict__ dst, int npairs) {
  int stride = gridDim.x * blockDim.x;
  for (int i = blockIdx.x * blockDim.x + threadIdx.x; i < npairs; i += stride) {
    const float4* p = reinterpret_cast<const float4*>(src) + (size_t)i * 4;
    float4 a = p[0];  // group 2i:   floats 0..3
    float4 b = p[2];  // group 2i+1: floats 0..3
    uint2 r;
    r.x = f2bf_rne(a.x) | (f2bf_rne(a.z) << 16);
    r.y = f2bf_rne(b.x) | (f2bf_rne(b.z) << 16);
    dst[i] = r;
  }
}

// ------- persistent 256x256 bf16 GEMM, counted-vmcnt ring across tiles -------
// A = Xg [MROWS][KEFF] bf16 row-major, B = Wg [DOUT][KEFF] bf16 row-major (B^T).
// C[m][n] = sum_k A[m][k]*B[n][k] + bias[n], fp32 row-major.
// Each block: fixed mblk, TPB consecutive nblk tiles -> 64-deep K pipeline.
#define BM 256
#define BN 256
#define BK 64
#define NT (KEFF / BK)   // 16
#define TPB 4            // output tiles per block

// LDS half-tile layout: [128 superrows][128B]; superrow sr holds rows 2sr,2sr+1
// (32 k-elems = 64B each), 8x16B slots XOR-swizzled by (sr&7).
__device__ __forceinline__ int swz_off(int R, int lg) {
  int sr = R >> 1;
  return sr * 128 + (((((R & 1) << 2) | lg) ^ (sr & 7)) << 4);
}

__global__ __launch_bounds__(512, 2) void venom_gemm(
    const __bf16* __restrict__ A, const __bf16* __restrict__ Bm,
    const float* __restrict__ bias, float* __restrict__ C) {
  // [dbuf][k-half][16KB half-tile] for A and B: 128 KiB total
  __shared__ __bf16 As[2][2][128 * 64];
  __shared__ __bf16 Bs[2][2][128 * 64];

  // grid = 256 = (MROWS/BM) * (DOUT/BN/TPB); XCD-bijective swizzle (256%8==0)
  int nwg = gridDim.x;
  int cpx = nwg >> 3;
  int bid = blockIdx.x;
  int swz = (bid & 7) * cpx + (bid >> 3);
  int mblk = swz >> 2;   // 0..63
  int ngrp = swz & 3;    // tile j covers nblk = ngrp*TPB + j

  int t = threadIdx.x;
  int wid = t >> 6, l = t & 63;
  int wr = wid >> 2, wc = wid & 3;   // 2x4 wave grid; wave owns 128x64 of C
  int lr = l & 15, lg = l >> 4;

  const __bf16* Ag = A + (size_t)(mblk * BM) * KEFF;

  // Preload bias into registers (static indexing only — rule #20).
  float biasr[TPB][4];
  #pragma unroll
  for (int j = 0; j < TPB; ++j)
    #pragma unroll
    for (int ni = 0; ni < 4; ++ni)
      biasr[j][ni] = bias[(ngrp * TPB + j) * BN + wc * 64 + ni * 16 + lr];

  f32x4 acc[8][4] = {};

  // Stage one k-half of iteration (j2,kt2): A 16KB + B 16KB = 4 loads/thread.
  // Linear LDS dest, inverse-swizzled global source (rule #21).
  auto stage_half = [&](int j2, int kt2, int kh) {
    const int buf = kt2 & 1;   // NT even -> parity continuous across tiles
    const __bf16* Bg = Bm + (size_t)((ngrp * TPB + j2) * BN) * KEFF;
    const int k0 = kt2 * BK + kh * 32;
    #pragma unroll
    for (int i = 0; i < 2; ++i) {
      int e = i * 512 + t;           // 16B chunk 0..1023
      int sr = e >> 3;
      int s = (e & 7) ^ (sr & 7);    // unswizzled slot
      int row = sr * 2 + (s >> 2);
      int koff = (s & 3) * 8;
      __builtin_amdgcn_global_load_lds(
          (const AS1 uint32_t*)(Ag + (size_t)row * KEFF + k0 + koff),
          ((AS3 uint32_t*)&As[buf][kh][0]) + e * 4, 16, 0, 0);
      __builtin_amdgcn_global_load_lds(
          (const AS1 uint32_t*)(Bg + (size_t)row * KEFF + k0 + koff),
          ((AS3 uint32_t*)&Bs[buf][kh][0]) + e * 4, 16, 0, 0);
    }
  };

  // Prologue: both halves of (0,0); keep newest 4 loads in flight.
  stage_half(0, 0, 0);
  stage_half(0, 0, 1);
  asm volatile("s_waitcnt vmcnt(4)" ::: "memory");
  __builtin_amdgcn_s_barrier();

  bf16x8 bfrag[4];

  #pragma unroll
  for (int j = 0; j < TPB; ++j) {          // j compile-time (full unroll)
    #pragma unroll 1
    for (int kt = 0; kt < NT; ++kt) {
      const int cur = kt & 1;
      const bool last_it = (j == TPB - 1) && (kt == NT - 1);
      const int j2  = (kt < NT - 1) ? j : j + 1;    // next iteration's tile
      const int kt2 = (kt < NT - 1) ? kt + 1 : 0;

      // Phases (mh,kh): (0,0),(1,0),(0,1),(1,1). Stage next iter's kh at 0,2.
      #pragma unroll
      for (int ph = 0; ph < 4; ++ph) {
        const int mh = ph & 1, kh = ph >> 1;
        const char* aB = (const char*)&As[cur][kh][0];
        bf16x8 af[4];
        #pragma unroll
        for (int mi = 0; mi < 4; ++mi)
          af[mi] = *(const bf16x8*)(aB + swz_off(wr * 128 + mh * 64 + mi * 16 + lr, lg));
        if (mh == 0) {
          const char* bB = (const char*)&Bs[cur][kh][0];
          #pragma unroll
          for (int ni = 0; ni < 4; ++ni)
            bfrag[ni] = *(const bf16x8*)(bB + swz_off(wc * 64 + ni * 16 + lr, lg));
          if (!last_it) stage_half(j2, kt2, kh);
        }

        __builtin_amdgcn_s_barrier();
        __builtin_amdgcn_s_setprio(1);
        #pragma unroll
        for (int mi = 0; mi < 4; ++mi)
          #pragma unroll
          for (int ni = 0; ni < 4; ++ni)
            acc[mh * 4 + mi][ni] = __builtin_amdgcn_mfma_f32_16x16x32_bf16(
                af[mi], bfrag[ni], acc[mh * 4 + mi][ni], 0, 0, 0);
        __builtin_amdgcn_s_setprio(0);

        if (ph == 1) {
          if (!last_it) asm volatile("s_waitcnt vmcnt(4)" ::: "memory");
          else          asm volatile("s_waitcnt vmcnt(0)" ::: "memory");
          __builtin_amdgcn_s_barrier();
        } else if (ph == 3) {
          if (!last_it) {
            asm volatile("s_waitcnt vmcnt(4)" ::: "memory");
            __builtin_amdgcn_s_barrier();
          }
        } else {
          __builtin_amdgcn_s_barrier();
        }
      }
    }

    // Epilogue for tile j (compile-time j -> static biasr index).
    // Registers/stores only; no LDS touch, so it overlaps the in-flight stage.
    {
      int colbase = (ngrp * TPB + j) * BN + wc * 64;
      int rowbase = mblk * BM + wr * 128;
      #pragma unroll
      for (int mh = 0; mh < 2; ++mh)
        #pragma unroll
        for (int mi = 0; mi < 4; ++mi) {
          int row0 = rowbase + mh * 64 + mi * 16 + lg * 4;
          #pragma unroll
          for (int ni = 0; ni < 4; ++ni) {
            int col = colbase + ni * 16 + lr;
            f32x4 cv = acc[mh * 4 + mi][ni];
            #pragma unroll
            for (int jj = 0; jj < 4; ++jj)
              C[(size_t)(row0 + jj) * DOUT + col] = cv[jj] + biasr[j][ni];
          }
        }
      #pragma unroll
      for (int q = 0; q < 8; ++q)
        #pragma unroll
        for (int ni = 0; ni < 4; ++ni)
          acc[q][ni] = (f32x4){0.f, 0.f, 0.f, 0.f};
    }
  }
}

// Correct-but-slow fallback if workspace is too small (should not trigger).
__global__ void venom_naive(const float* __restrict__ x, const float* __restrict__ w,
                            const float* __restrict__ bias, float* __restrict__ out) {
  size_t total = (size_t)MROWS * DOUT;
  size_t stride = (size_t)gridDim.x * blockDim.x;
  for (size_t idx = (size_t)blockIdx.x * blockDim.x + threadIdx.x; idx < total;
       idx += stride) {
    int m = (int)(idx / DOUT), n = (int)(idx % DOUT);
    const float* xr = x + (size_t)m * DIN;
    const float* wr = w + (size_t)n * DIN;
    float s = 0.f;
    for (int g = 0; g < DIN / 8; ++g)
      s += xr[g * 8] * wr[g * 8] + xr[g * 8 + 2] * wr[g * 8 + 2];
    out[idx] = s + bias[n];
  }
}

extern "C" void kernel_launch(void* const* d_in, const int* in_sizes, int n_in,
                              void* d_out, int out_size, void* d_ws, size_t ws_size,
                              hipStream_t stream) {
  const float* x    = (const float*)d_in[0];
  const float* wgt  = (const float*)d_in[1];
  const float* bias = (const float*)d_in[2];
  float* out = (float*)d_out;

  const size_t xg_bytes = (size_t)MROWS * KEFF * 2;  // 33.5 MB
  const size_t wg_bytes = (size_t)DOUT * KEFF * 2;   //  8.4 MB

  if (ws_size < xg_bytes + wg_bytes) {
    venom_naive<<<2048, 256, 0, stream>>>(x, wgt, bias, out);
    return;
  }

  uint32_t* xg = (uint32_t*)d_ws;
  uint32_t* wg = (uint32_t*)((char*)d_ws + xg_bytes);

  venom_gather2<<<2048, 256, 0, stream>>>(x, (uint2*)xg, MROWS * (DIN / 16));
  venom_gather2<<<1024, 256, 0, stream>>>(wgt, (uint2*)wg, DOUT * (DIN / 16));

  venom_gemm<<<(MROWS / BM) * (DOUT / BN / TPB), 512, 0, stream>>>(
      (const __bf16*)xg, (const __bf16*)wg, bias, out);
}